// Round 2
// baseline (319.774 us; speedup 1.0000x reference)
//
#include <hip/hip_runtime.h>
#include <stdint.h>

typedef int v4i  __attribute__((ext_vector_type(4)));
typedef int v16i __attribute__((ext_vector_type(16)));

// ---------------------------------------------------------------------------
// Kernel 1: quantize activations fp32 -> int8, plus per-row sums.
// ---------------------------------------------------------------------------
__global__ void quant_x_kernel(const float* __restrict__ x,
                               int8_t* __restrict__ xq,
                               int* __restrict__ sum_x,
                               const float* __restrict__ p_scale,
                               const int* __restrict__ p_zp,
                               int K) {
    const int row = blockIdx.x;
    const int t = threadIdx.x;
    const float s = p_scale[0];
    const float zpf = (float)p_zp[0];
    const float* xr = x + (size_t)row * K;
    int8_t* qr = xq + (size_t)row * K;
    int lsum = 0;
    const int nchunk = K >> 10;              // each pass covers 256 thr * 4 elems
    for (int i = 0; i < nchunk; ++i) {
        const int idx = (i << 10) + (t << 2);
        const float4 v = *reinterpret_cast<const float4*>(xr + idx);
        // division (not mul-by-reciprocal) to match jnp rounding; rintf = half-to-even
        const float f0 = fminf(fmaxf(rintf(v.x / s) + zpf, -128.f), 127.f);
        const float f1 = fminf(fmaxf(rintf(v.y / s) + zpf, -128.f), 127.f);
        const float f2 = fminf(fmaxf(rintf(v.z / s) + zpf, -128.f), 127.f);
        const float f3 = fminf(fmaxf(rintf(v.w / s) + zpf, -128.f), 127.f);
        const int i0 = (int)f0, i1 = (int)f1, i2 = (int)f2, i3 = (int)f3;
        lsum += i0 + i1 + i2 + i3;
        const unsigned pk = (unsigned)(i0 & 255) | ((unsigned)(i1 & 255) << 8) |
                            ((unsigned)(i2 & 255) << 16) | ((unsigned)(i3 & 255) << 24);
        *reinterpret_cast<unsigned*>(qr + idx) = pk;
    }
    __shared__ int wsum[4];
    #pragma unroll
    for (int off = 32; off > 0; off >>= 1) lsum += __shfl_down(lsum, off);
    if ((t & 63) == 0) wsum[t >> 6] = lsum;
    __syncthreads();
    if (t == 0) sum_x[row] = wsum[0] + wsum[1] + wsum[2] + wsum[3];
}

// ---------------------------------------------------------------------------
// Kernel 2: pack weight int32 (int8-valued) -> int8, plus per-row sums.
// ---------------------------------------------------------------------------
__global__ void quant_w_kernel(const int* __restrict__ w,
                               int8_t* __restrict__ wq,
                               int* __restrict__ sum_w,
                               int K) {
    const int row = blockIdx.x;
    const int t = threadIdx.x;
    const int* wr_ = w + (size_t)row * K;
    int8_t* qr = wq + (size_t)row * K;
    int lsum = 0;
    const int nchunk = K >> 10;
    for (int i = 0; i < nchunk; ++i) {
        const int idx = (i << 10) + (t << 2);
        const int4 v = *reinterpret_cast<const int4*>(wr_ + idx);
        lsum += v.x + v.y + v.z + v.w;
        const unsigned pk = (unsigned)(v.x & 255) | ((unsigned)(v.y & 255) << 8) |
                            ((unsigned)(v.z & 255) << 16) | ((unsigned)(v.w & 255) << 24);
        *reinterpret_cast<unsigned*>(qr + idx) = pk;
    }
    __shared__ int wsum[4];
    #pragma unroll
    for (int off = 32; off > 0; off >>= 1) lsum += __shfl_down(lsum, off);
    if ((t & 63) == 0) wsum[t >> 6] = lsum;
    __syncthreads();
    if (t == 0) sum_w[row] = wsum[0] + wsum[1] + wsum[2] + wsum[3];
}

// ---------------------------------------------------------------------------
// Kernel 3: int8 GEMM via global_load_lds staging (m97 structure).
// 128x128 tile, BK=64, 4 waves, wave = 64x64 = 2x2 frags of 32x32x32 i8.
//
// LDS fragment-major: frag fi = ks*4 + rb stores lane l's 16B chunk at
// fi*1024 + l*16, where chunk = row rb*32+(l&31), kbytes ks*32+(l>>5)*16.
// This IS the wave-linear order global_load_lds produces (uniform LDS base +
// lane*16) -- so staging = 4 global_load_lds_dwordx4 per wave with per-lane
// pre-swizzled global addresses. No ds_write, no staging VGPRs.
// ---------------------------------------------------------------------------
#define BM 128
#define BN 128
#define BK 64

__device__ __forceinline__ void gload_lds16(const void* g, void* l) {
    __builtin_amdgcn_global_load_lds(
        (const __attribute__((address_space(1))) unsigned int*)g,
        (__attribute__((address_space(3))) unsigned int*)l, 16, 0, 0);
}

__global__ __launch_bounds__(256, 2)
void gemm_i8_kernel(const int8_t* __restrict__ xq,
                    const int8_t* __restrict__ wq,
                    const int* __restrict__ sum_x,
                    const int* __restrict__ sum_w,
                    const float* __restrict__ bias,
                    float* __restrict__ out,
                    const float* __restrict__ p_sa,
                    const int* __restrict__ p_zpa,
                    const float* __restrict__ p_sw,
                    const int* __restrict__ p_wzp,
                    int M, int N, int K) {
    __shared__ v4i ldsA[2][512];   // 2 buf * 8 frags * 64 chunks (8KB/buf)
    __shared__ v4i ldsB[2][512];

    const int tid = threadIdx.x;
    const int lane = tid & 63;
    const int wid = tid >> 6;
    const int wr = wid >> 1;           // wave row 0..1  (64 rows each)
    const int wc = wid & 1;            // wave col 0..1  (64 cols each)
    const int m0 = blockIdx.y * BM;
    const int n0 = blockIdx.x * BN;

    // Staging: wave w owns row-block rb=w of both operands, both k-halves.
    // frag fi: {w, w+4}. Per-lane global src: row w*32+(lane&31), kbyte (lane>>5)*16.
    const int8_t* aS = xq + (size_t)(m0 + wid * 32 + (lane & 31)) * K + ((lane >> 5) << 4);
    const int8_t* bS = wq + (size_t)(n0 + wid * 32 + (lane & 31)) * K + ((lane >> 5) << 4);

    v16i acc[2][2] = {};
    const int NT = K / BK;

    // prologue: stage tile 0 into buf 0
    gload_lds16(aS,      &ldsA[0][wid * 64]);
    gload_lds16(aS + 32, &ldsA[0][(wid + 4) * 64]);
    gload_lds16(bS,      &ldsB[0][wid * 64]);
    gload_lds16(bS + 32, &ldsB[0][(wid + 4) * 64]);

    int cur = 0;
    for (int t = 0; t < NT; ++t) {
        __syncthreads();   // drains vmcnt+lgkm: buf[cur] staged, buf[cur^1] readers done
        if (t + 1 < NT) {
            const int nb = cur ^ 1;
            const int koff = (t + 1) * BK;
            gload_lds16(aS + koff,      &ldsA[nb][wid * 64]);
            gload_lds16(aS + koff + 32, &ldsA[nb][(wid + 4) * 64]);
            gload_lds16(bS + koff,      &ldsB[nb][wid * 64]);
            gload_lds16(bS + koff + 32, &ldsB[nb][(wid + 4) * 64]);
        }
        #pragma unroll
        for (int ks = 0; ks < 2; ++ks) {
            const v4i a0 = ldsA[cur][(ks * 4 + wr * 2 + 0) * 64 + lane];
            const v4i a1 = ldsA[cur][(ks * 4 + wr * 2 + 1) * 64 + lane];
            const v4i b0 = ldsB[cur][(ks * 4 + wc * 2 + 0) * 64 + lane];
            const v4i b1 = ldsB[cur][(ks * 4 + wc * 2 + 1) * 64 + lane];
            acc[0][0] = __builtin_amdgcn_mfma_i32_32x32x32_i8(a0, b0, acc[0][0], 0, 0, 0);
            acc[0][1] = __builtin_amdgcn_mfma_i32_32x32x32_i8(a0, b1, acc[0][1], 0, 0, 0);
            acc[1][0] = __builtin_amdgcn_mfma_i32_32x32x32_i8(a1, b0, acc[1][0], 0, 0, 0);
            acc[1][1] = __builtin_amdgcn_mfma_i32_32x32x32_i8(a1, b1, acc[1][1], 0, 0, 0);
        }
        cur ^= 1;
    }

    // epilogue: y = (acc - wzp*sum_x[m] - zp*sum_w[n] + K*zp*wzp) * (sa*sw) + bias[n]
    const float stot = p_sa[0] * p_sw[0];
    const int zpa = p_zpa[0];
    const int wzp = p_wzp[0];
    const int kzz = K * zpa * wzp;
    const int coll = lane & 31;
    const int rhi = (lane >> 5) * 4;

    #pragma unroll
    for (int nf = 0; nf < 2; ++nf) {
        const int cg = n0 + wc * 64 + nf * 32 + coll;
        const int sw = sum_w[cg];
        const float bb = bias[cg];
        #pragma unroll
        for (int mf = 0; mf < 2; ++mf) {
            const int rbase = m0 + wr * 64 + mf * 32 + rhi;
            #pragma unroll
            for (int r = 0; r < 16; ++r) {
                const int rowg = rbase + (r & 3) + 8 * (r >> 2);
                const int iv = acc[mf][nf][r] - wzp * sum_x[rowg] - zpa * sw + kzz;
                out[(size_t)rowg * N + cg] = (float)iv * stot + bb;
            }
        }
    }
}

// ---------------------------------------------------------------------------
extern "C" void kernel_launch(void* const* d_in, const int* in_sizes, int n_in,
                              void* d_out, int out_size, void* d_ws, size_t ws_size,
                              hipStream_t stream) {
    const float* x     = (const float*)d_in[0];
    const int*   w     = (const int*)d_in[1];
    const float* bias  = (const float*)d_in[2];
    const float* p_sa  = (const float*)d_in[3];
    const int*   p_zpa = (const int*)d_in[4];
    const float* p_sw  = (const float*)d_in[5];
    const int*   p_wzp = (const int*)d_in[6];

    const int N = in_sizes[2];             // OUT
    const int K = in_sizes[1] / N;         // IN
    const int M = in_sizes[0] / K;         // B*S

    // workspace layout: xq[M*K] i8 | wq[N*K] i8 | sum_x[M] i32 | sum_w[N] i32
    int8_t* xq = (int8_t*)d_ws;
    int8_t* wq = xq + (size_t)M * K;
    int* sum_x = (int*)(wq + (size_t)N * K);
    int* sum_w = sum_x + M;

    quant_x_kernel<<<M, 256, 0, stream>>>(x, xq, sum_x, p_sa, p_zpa, K);
    quant_w_kernel<<<N, 256, 0, stream>>>(w, wq, sum_w, K);

    dim3 grid(N / BN, M / BM);
    gemm_i8_kernel<<<grid, 256, 0, stream>>>(xq, wq, sum_x, sum_w, bias,
                                             (float*)d_out, p_sa, p_zpa, p_sw, p_wzp,
                                             M, N, K);
}

// Round 3
// 250.981 us; speedup vs baseline: 1.2741x; 1.2741x over previous
//
#include <hip/hip_runtime.h>
#include <stdint.h>

typedef int v4i  __attribute__((ext_vector_type(4)));
typedef int v16i __attribute__((ext_vector_type(16)));

// ---------------------------------------------------------------------------
// Kernel 1: quantize activations fp32 -> int8, plus per-row sums.
// ---------------------------------------------------------------------------
__global__ void quant_x_kernel(const float* __restrict__ x,
                               int8_t* __restrict__ xq,
                               int* __restrict__ sum_x,
                               const float* __restrict__ p_scale,
                               const int* __restrict__ p_zp,
                               int K) {
    const int row = blockIdx.x;
    const int t = threadIdx.x;
    const float s = p_scale[0];
    const float zpf = (float)p_zp[0];
    const float* xr = x + (size_t)row * K;
    int8_t* qr = xq + (size_t)row * K;
    int lsum = 0;
    const int nchunk = K >> 10;
    for (int i = 0; i < nchunk; ++i) {
        const int idx = (i << 10) + (t << 2);
        const float4 v = *reinterpret_cast<const float4*>(xr + idx);
        const float f0 = fminf(fmaxf(rintf(v.x / s) + zpf, -128.f), 127.f);
        const float f1 = fminf(fmaxf(rintf(v.y / s) + zpf, -128.f), 127.f);
        const float f2 = fminf(fmaxf(rintf(v.z / s) + zpf, -128.f), 127.f);
        const float f3 = fminf(fmaxf(rintf(v.w / s) + zpf, -128.f), 127.f);
        const int i0 = (int)f0, i1 = (int)f1, i2 = (int)f2, i3 = (int)f3;
        lsum += i0 + i1 + i2 + i3;
        const unsigned pk = (unsigned)(i0 & 255) | ((unsigned)(i1 & 255) << 8) |
                            ((unsigned)(i2 & 255) << 16) | ((unsigned)(i3 & 255) << 24);
        *reinterpret_cast<unsigned*>(qr + idx) = pk;
    }
    __shared__ int wsum[4];
    #pragma unroll
    for (int off = 32; off > 0; off >>= 1) lsum += __shfl_down(lsum, off);
    if ((t & 63) == 0) wsum[t >> 6] = lsum;
    __syncthreads();
    if (t == 0) sum_x[row] = wsum[0] + wsum[1] + wsum[2] + wsum[3];
}

// ---------------------------------------------------------------------------
// Kernel 2: pack weight int32 (int8-valued) -> int8, plus per-row sums.
// ---------------------------------------------------------------------------
__global__ void quant_w_kernel(const int* __restrict__ w,
                               int8_t* __restrict__ wq,
                               int* __restrict__ sum_w,
                               int K) {
    const int row = blockIdx.x;
    const int t = threadIdx.x;
    const int* wr_ = w + (size_t)row * K;
    int8_t* qr = wq + (size_t)row * K;
    int lsum = 0;
    const int nchunk = K >> 10;
    for (int i = 0; i < nchunk; ++i) {
        const int idx = (i << 10) + (t << 2);
        const int4 v = *reinterpret_cast<const int4*>(wr_ + idx);
        lsum += v.x + v.y + v.z + v.w;
        const unsigned pk = (unsigned)(v.x & 255) | ((unsigned)(v.y & 255) << 8) |
                            ((unsigned)(v.z & 255) << 16) | ((unsigned)(v.w & 255) << 24);
        *reinterpret_cast<unsigned*>(qr + idx) = pk;
    }
    __shared__ int wsum[4];
    #pragma unroll
    for (int off = 32; off > 0; off >>= 1) lsum += __shfl_down(lsum, off);
    if ((t & 63) == 0) wsum[t >> 6] = lsum;
    __syncthreads();
    if (t == 0) sum_w[row] = wsum[0] + wsum[1] + wsum[2] + wsum[3];
}

// ---------------------------------------------------------------------------
// Kernel 3: int8 GEMM, 256x256 tile, phase-split counted-vmcnt schedule
// (T2 swizzle + T3/T4 counted pipeline + T5 setprio), 8 waves.
//
// LDS: 4 slots x [256 rows][64 B] per operand (128 KiB total). Pipeline
// distance 2 K-tiles: tile t is computed from slot t&3 while tile t+2 is
// staged into slot (t+2)&3. vmcnt(4) once per K-tile (never 0 in-loop).
//
// T2 swizzle (both-sides, rule 21): 16B-chunk' = chunk ^ (row&3). Staged via
// global_load_lds with LINEAR LDS dest + inverse-swizzled per-lane SOURCE
// (4-lane groups still read one contiguous 64B row-slice -> coalescing
// preserved); ds_read applies the same XOR -> 8 words/bank (the floor).
// ---------------------------------------------------------------------------
#define BM 256
#define BN 256
#define BKB 64
#define NSLOT 4

__device__ __forceinline__ void gload_lds16(const void* g, void* l) {
    __builtin_amdgcn_global_load_lds(
        (const __attribute__((address_space(1))) unsigned int*)g,
        (__attribute__((address_space(3))) unsigned int*)l, 16, 0, 0);
}

#define MFMA_I8 __builtin_amdgcn_mfma_i32_32x32x32_i8

__global__ __launch_bounds__(512, 2)
void gemm_i8_kernel(const int8_t* __restrict__ xq,
                    const int8_t* __restrict__ wq,
                    const int* __restrict__ sum_x,
                    const int* __restrict__ sum_w,
                    const float* __restrict__ bias,
                    float* __restrict__ out,
                    const float* __restrict__ p_sa,
                    const int* __restrict__ p_zpa,
                    const float* __restrict__ p_sw,
                    const int* __restrict__ p_wzp,
                    int M, int N, int K) {
    __shared__ v4i ldsA[NSLOT][1024];   // 4 slots * 16KB
    __shared__ v4i ldsB[NSLOT][1024];

    const int tid = threadIdx.x;
    const int lane = tid & 63;
    const int wid = tid >> 6;
    const int wr = wid >> 2;            // 0..1: rows wr*128..+127
    const int wc = wid & 3;             // 0..3: cols wc*64..+63
    const int m0 = blockIdx.y * BM;
    const int n0 = blockIdx.x * BN;

    // ---- staging constants: thread tid fills LDS chunk p = i*512 + tid.
    // decode: row = i*128 + (tid>>2), chunk' = tid&3; source chunk = chunk'^(row&3)
    const int srow = tid >> 2;                       // 0..127
    const int schunk = (tid & 3) ^ (srow & 3);       // inverse-swizzled src chunk
    const int8_t* aS = xq + (size_t)(m0 + srow) * K + schunk * 16;
    const int8_t* bS = wq + (size_t)(n0 + srow) * K + schunk * 16;
    const size_t half = (size_t)128 * K;             // +128 rows
    const int dbase = wid * 64;                      // wave-uniform LDS chunk base

    // ---- fragment-read constants: lane l reads row rb*32+(l&31),
    // chunk (ks*2 + (l>>5)) ^ (row&3); row&3 == lane&3 here.
    const int sel = lane & 3;
    const int hi = lane >> 5;
    const int abase = (wr * 128 + (lane & 31)) * 4;  // chunk index base
    const int bbase = (wc * 64 + (lane & 31)) * 4;
    const int c00 = hi ^ sel;          // ks0 chunk (pre-XOR)
    const int c01 = (2 + hi) ^ sel;    // ks1 chunk

    v16i acc[4][2] = {};
    const int NT = K / BKB;

    // ---- prologue: stage tiles 0 and 1
    gload_lds16(aS,             &ldsA[0][dbase]);
    gload_lds16(aS + half,      &ldsA[0][dbase + 512]);
    gload_lds16(bS,             &ldsB[0][dbase]);
    gload_lds16(bS + half,      &ldsB[0][dbase + 512]);
    gload_lds16(aS + 64,        &ldsA[1][dbase]);
    gload_lds16(aS + half + 64, &ldsA[1][dbase + 512]);
    gload_lds16(bS + 64,        &ldsB[1][dbase]);
    gload_lds16(bS + half + 64, &ldsB[1][dbase + 512]);
    asm volatile("s_waitcnt vmcnt(4)" ::: "memory");   // tile 0 landed
    __builtin_amdgcn_sched_barrier(0);
    __builtin_amdgcn_s_barrier();

    for (int t = 0; t < NT; ++t) {
        const v4i* LA = ldsA[t & 3];
        const v4i* LB = ldsB[t & 3];

        // ================= phase 0: B(all) + A rf0,rf1; stage A of t+2 ======
        const v4i b00 = LB[bbase + c00];
        const v4i b01 = LB[bbase + c01];
        const v4i b10 = LB[bbase + 128 + c00];
        const v4i b11 = LB[bbase + 128 + c01];
        const v4i a00 = LA[abase + c00];
        const v4i a01 = LA[abase + c01];
        const v4i a10 = LA[abase + 128 + c00];
        const v4i a11 = LA[abase + 128 + c01];
        if (t + 2 < NT) {
            const int ns = (t + 2) & 3;
            const int8_t* p = aS + (size_t)(t + 2) * BKB;
            gload_lds16(p,        &ldsA[ns][dbase]);
            gload_lds16(p + half, &ldsA[ns][dbase + 512]);
        }
        __builtin_amdgcn_s_barrier();
        __builtin_amdgcn_s_setprio(1);
        acc[0][0] = MFMA_I8(a00, b00, acc[0][0], 0, 0, 0);
        acc[0][1] = MFMA_I8(a00, b10, acc[0][1], 0, 0, 0);
        acc[1][0] = MFMA_I8(a10, b00, acc[1][0], 0, 0, 0);
        acc[1][1] = MFMA_I8(a10, b10, acc[1][1], 0, 0, 0);
        acc[0][0] = MFMA_I8(a01, b01, acc[0][0], 0, 0, 0);
        acc[0][1] = MFMA_I8(a01, b11, acc[0][1], 0, 0, 0);
        acc[1][0] = MFMA_I8(a11, b01, acc[1][0], 0, 0, 0);
        acc[1][1] = MFMA_I8(a11, b11, acc[1][1], 0, 0, 0);
        __builtin_amdgcn_s_setprio(0);
        __builtin_amdgcn_s_barrier();

        // ================= phase 1: A rf2,rf3; stage B of t+2 ===============
        const v4i a20 = LA[abase + 256 + c00];
        const v4i a21 = LA[abase + 256 + c01];
        const v4i a30 = LA[abase + 384 + c00];
        const v4i a31 = LA[abase + 384 + c01];
        if (t + 2 < NT) {
            const int ns = (t + 2) & 3;
            const int8_t* p = bS + (size_t)(t + 2) * BKB;
            gload_lds16(p,        &ldsB[ns][dbase]);
            gload_lds16(p + half, &ldsB[ns][dbase + 512]);
        }
        __builtin_amdgcn_s_barrier();
        __builtin_amdgcn_s_setprio(1);
        acc[2][0] = MFMA_I8(a20, b00, acc[2][0], 0, 0, 0);
        acc[2][1] = MFMA_I8(a20, b10, acc[2][1], 0, 0, 0);
        acc[3][0] = MFMA_I8(a30, b00, acc[3][0], 0, 0, 0);
        acc[3][1] = MFMA_I8(a30, b10, acc[3][1], 0, 0, 0);
        acc[2][0] = MFMA_I8(a21, b01, acc[2][0], 0, 0, 0);
        acc[2][1] = MFMA_I8(a21, b11, acc[2][1], 0, 0, 0);
        acc[3][0] = MFMA_I8(a31, b01, acc[3][0], 0, 0, 0);
        acc[3][1] = MFMA_I8(a31, b11, acc[3][1], 0, 0, 0);
        __builtin_amdgcn_s_setprio(0);
        // counted wait: tile t+1's 4 loads are the oldest; keep t+2's 4 in flight
        if (t + 2 < NT) {
            asm volatile("s_waitcnt vmcnt(4)" ::: "memory");
        } else if (t + 1 < NT) {
            asm volatile("s_waitcnt vmcnt(0)" ::: "memory");
        }
        __builtin_amdgcn_sched_barrier(0);
        __builtin_amdgcn_s_barrier();
    }

    // ---- epilogue: y = (acc - wzp*sum_x[m] - zp*sum_w[n] + K*zp*wzp)*(sa*sw) + bias[n]
    const float stot = p_sa[0] * p_sw[0];
    const int zpa = p_zpa[0];
    const int wzp = p_wzp[0];
    const int kzz = K * zpa * wzp;
    const int coll = lane & 31;
    const int rhi = (lane >> 5) * 4;

    #pragma unroll
    for (int cf = 0; cf < 2; ++cf) {
        const int cg = n0 + wc * 64 + cf * 32 + coll;
        const int sw = sum_w[cg];
        const float bb = bias[cg];
        #pragma unroll
        for (int rf = 0; rf < 4; ++rf) {
            const int rbase = m0 + wr * 128 + rf * 32 + rhi;
            #pragma unroll
            for (int r = 0; r < 16; ++r) {
                const int rowg = rbase + (r & 3) + 8 * (r >> 2);
                const int iv = acc[rf][cf][r] - wzp * sum_x[rowg] - zpa * sw + kzz;
                out[(size_t)rowg * N + cg] = (float)iv * stot + bb;
            }
        }
    }
}

// ---------------------------------------------------------------------------
extern "C" void kernel_launch(void* const* d_in, const int* in_sizes, int n_in,
                              void* d_out, int out_size, void* d_ws, size_t ws_size,
                              hipStream_t stream) {
    const float* x     = (const float*)d_in[0];
    const int*   w     = (const int*)d_in[1];
    const float* bias  = (const float*)d_in[2];
    const float* p_sa  = (const float*)d_in[3];
    const int*   p_zpa = (const int*)d_in[4];
    const float* p_sw  = (const float*)d_in[5];
    const int*   p_wzp = (const int*)d_in[6];

    const int N = in_sizes[2];             // OUT
    const int K = in_sizes[1] / N;         // IN
    const int M = in_sizes[0] / K;         // B*S

    int8_t* xq = (int8_t*)d_ws;
    int8_t* wq = xq + (size_t)M * K;
    int* sum_x = (int*)(wq + (size_t)N * K);
    int* sum_w = sum_x + M;

    quant_x_kernel<<<M, 256, 0, stream>>>(x, xq, sum_x, p_sa, p_zpa, K);
    quant_w_kernel<<<N, 256, 0, stream>>>(w, wq, sum_w, K);

    dim3 grid(N / BN, M / BM);
    gemm_i8_kernel<<<grid, 512, 0, stream>>>(xq, wq, sum_x, sum_w, bias,
                                             (float*)d_out, p_sa, p_zpa, p_sw, p_wzp,
                                             M, N, K);
}

// Round 4
// 239.020 us; speedup vs baseline: 1.3379x; 1.0500x over previous
//
#include <hip/hip_runtime.h>
#include <stdint.h>

typedef int v4i  __attribute__((ext_vector_type(4)));
typedef int v16i __attribute__((ext_vector_type(16)));

// ---------------------------------------------------------------------------
// Kernel 1: quantize activations fp32 -> int8, plus per-row sums.
// ---------------------------------------------------------------------------
__global__ void quant_x_kernel(const float* __restrict__ x,
                               int8_t* __restrict__ xq,
                               int* __restrict__ sum_x,
                               const float* __restrict__ p_scale,
                               const int* __restrict__ p_zp,
                               int K) {
    const int row = blockIdx.x;
    const int t = threadIdx.x;
    const float s = p_scale[0];
    const float zpf = (float)p_zp[0];
    const float* xr = x + (size_t)row * K;
    int8_t* qr = xq + (size_t)row * K;
    int lsum = 0;
    const int nchunk = K >> 10;
    for (int i = 0; i < nchunk; ++i) {
        const int idx = (i << 10) + (t << 2);
        const float4 v = *reinterpret_cast<const float4*>(xr + idx);
        const float f0 = fminf(fmaxf(rintf(v.x / s) + zpf, -128.f), 127.f);
        const float f1 = fminf(fmaxf(rintf(v.y / s) + zpf, -128.f), 127.f);
        const float f2 = fminf(fmaxf(rintf(v.z / s) + zpf, -128.f), 127.f);
        const float f3 = fminf(fmaxf(rintf(v.w / s) + zpf, -128.f), 127.f);
        const int i0 = (int)f0, i1 = (int)f1, i2 = (int)f2, i3 = (int)f3;
        lsum += i0 + i1 + i2 + i3;
        const unsigned pk = (unsigned)(i0 & 255) | ((unsigned)(i1 & 255) << 8) |
                            ((unsigned)(i2 & 255) << 16) | ((unsigned)(i3 & 255) << 24);
        *reinterpret_cast<unsigned*>(qr + idx) = pk;
    }
    __shared__ int wsum[4];
    #pragma unroll
    for (int off = 32; off > 0; off >>= 1) lsum += __shfl_down(lsum, off);
    if ((t & 63) == 0) wsum[t >> 6] = lsum;
    __syncthreads();
    if (t == 0) sum_x[row] = wsum[0] + wsum[1] + wsum[2] + wsum[3];
}

// ---------------------------------------------------------------------------
// Kernel 2: pack weight int32 (int8-valued) -> int8, plus per-row sums.
// ---------------------------------------------------------------------------
__global__ void quant_w_kernel(const int* __restrict__ w,
                               int8_t* __restrict__ wq,
                               int* __restrict__ sum_w,
                               int K) {
    const int row = blockIdx.x;
    const int t = threadIdx.x;
    const int* wr_ = w + (size_t)row * K;
    int8_t* qr = wq + (size_t)row * K;
    int lsum = 0;
    const int nchunk = K >> 10;
    for (int i = 0; i < nchunk; ++i) {
        const int idx = (i << 10) + (t << 2);
        const int4 v = *reinterpret_cast<const int4*>(wr_ + idx);
        lsum += v.x + v.y + v.z + v.w;
        const unsigned pk = (unsigned)(v.x & 255) | ((unsigned)(v.y & 255) << 8) |
                            ((unsigned)(v.z & 255) << 16) | ((unsigned)(v.w & 255) << 24);
        *reinterpret_cast<unsigned*>(qr + idx) = pk;
    }
    __shared__ int wsum[4];
    #pragma unroll
    for (int off = 32; off > 0; off >>= 1) lsum += __shfl_down(lsum, off);
    if ((t & 63) == 0) wsum[t >> 6] = lsum;
    __syncthreads();
    if (t == 0) sum_w[row] = wsum[0] + wsum[1] + wsum[2] + wsum[3];
}

// ---------------------------------------------------------------------------
// Kernel 3: int8 GEMM, 256x256 tile, phase-split counted-vmcnt schedule
// (T2 swizzle + T3/T4 counted pipeline + T5 setprio), 8 waves.
//
// LDS: 4 slots x [256 rows][4 chunks of 16B] per operand (128 KiB total).
// Pipeline distance 2 K-tiles; vmcnt(4) once per K-tile (never 0 in-loop).
//
// T2 swizzle, f(row) = (row>>1)&3: stored chunk' = chunk ^ f(row).
// Bank-quad of chunk p = p mod 8 = 4*(row&1) + chunk'. With f = (row>>1)&3,
// lanes 0..7 of a fragment read (row = base + (l&31), fixed logical chunk)
// map to quads 0,4,1,5,2,6,3,7 -- all 8 distinct -> conflict-free ds_read.
// (Round-3 bug: f(row)=row&3 made quad depend only on l&1,l&3 -> 4 quads,
// 2-way conflict on EVERY read -> the measured 3.78e7 SQ_LDS_BANK_CONFLICT.)
// Staged via global_load_lds: LINEAR LDS dest (quad = lane mod 8, uniform),
// inverse-swizzled per-lane SOURCE chunk (permutation within one contiguous
// 64B row-slice per 4-lane group -> coalescing preserved). Rule 21 holds:
// source permutation == read permutation.
// ---------------------------------------------------------------------------
#define BM 256
#define BN 256
#define BKB 64
#define NSLOT 4

__device__ __forceinline__ void gload_lds16(const void* g, void* l) {
    __builtin_amdgcn_global_load_lds(
        (const __attribute__((address_space(1))) unsigned int*)g,
        (__attribute__((address_space(3))) unsigned int*)l, 16, 0, 0);
}

#define MFMA_I8 __builtin_amdgcn_mfma_i32_32x32x32_i8

__global__ __launch_bounds__(512, 2)
void gemm_i8_kernel(const int8_t* __restrict__ xq,
                    const int8_t* __restrict__ wq,
                    const int* __restrict__ sum_x,
                    const int* __restrict__ sum_w,
                    const float* __restrict__ bias,
                    float* __restrict__ out,
                    const float* __restrict__ p_sa,
                    const int* __restrict__ p_zpa,
                    const float* __restrict__ p_sw,
                    const int* __restrict__ p_wzp,
                    int M, int N, int K) {
    __shared__ v4i ldsA[NSLOT][1024];   // 4 slots * 16KB
    __shared__ v4i ldsB[NSLOT][1024];

    const int tid = threadIdx.x;
    const int lane = tid & 63;
    const int wid = tid >> 6;
    const int wr = wid >> 2;            // 0..1: rows wr*128..+127
    const int wc = wid & 3;             // 0..3: cols wc*64..+63
    const int m0 = blockIdx.y * BM;
    const int n0 = blockIdx.x * BN;

    // ---- staging: thread tid fills LDS chunk p = i*512 + tid.
    // row = i*128 + (tid>>2), stored chunk' = tid&3; source logical chunk =
    // chunk' ^ f(row) with f(row) = (row>>1)&3  (i*128 doesn't affect f).
    const int srow = tid >> 2;                          // 0..127
    const int schunk = (tid & 3) ^ ((srow >> 1) & 3);   // inverse-swizzled src
    const int8_t* aS = xq + (size_t)(m0 + srow) * K + schunk * 16;
    const int8_t* bS = wq + (size_t)(n0 + srow) * K + schunk * 16;
    const size_t half = (size_t)128 * K;                // +128 rows
    const int dbase = wid * 64;                         // wave-uniform LDS base

    // ---- fragment reads: lane l, row = rbase + (l&31), logical chunk
    // c = ks*2 + (l>>5); stored at c ^ f(row), f(row) = ((l&31)>>1)&3.
    const int sel = (lane >> 1) & 3;                    // == ((lane&31)>>1)&3
    const int hi = lane >> 5;
    const int abase = (wr * 128 + (lane & 31)) * 4;     // chunk index base
    const int bbase = (wc * 64 + (lane & 31)) * 4;
    const int c00 = hi ^ sel;          // ks0 stored chunk
    const int c01 = (2 + hi) ^ sel;    // ks1 stored chunk

    v16i acc[4][2] = {};
    const int NT = K / BKB;

    // ---- prologue: stage tiles 0 and 1
    gload_lds16(aS,             &ldsA[0][dbase]);
    gload_lds16(aS + half,      &ldsA[0][dbase + 512]);
    gload_lds16(bS,             &ldsB[0][dbase]);
    gload_lds16(bS + half,      &ldsB[0][dbase + 512]);
    gload_lds16(aS + 64,        &ldsA[1][dbase]);
    gload_lds16(aS + half + 64, &ldsA[1][dbase + 512]);
    gload_lds16(bS + 64,        &ldsB[1][dbase]);
    gload_lds16(bS + half + 64, &ldsB[1][dbase + 512]);
    asm volatile("s_waitcnt vmcnt(4)" ::: "memory");   // tile 0 landed
    __builtin_amdgcn_sched_barrier(0);
    __builtin_amdgcn_s_barrier();

    for (int t = 0; t < NT; ++t) {
        const v4i* LA = ldsA[t & 3];
        const v4i* LB = ldsB[t & 3];

        // ================= phase 0: B(all) + A rf0,rf1; stage A of t+2 ======
        const v4i b00 = LB[bbase + c00];
        const v4i b01 = LB[bbase + c01];
        const v4i b10 = LB[bbase + 128 + c00];
        const v4i b11 = LB[bbase + 128 + c01];
        const v4i a00 = LA[abase + c00];
        const v4i a01 = LA[abase + c01];
        const v4i a10 = LA[abase + 128 + c00];
        const v4i a11 = LA[abase + 128 + c01];
        if (t + 2 < NT) {
            const int ns = (t + 2) & 3;
            const int8_t* p = aS + (size_t)(t + 2) * BKB;
            gload_lds16(p,        &ldsA[ns][dbase]);
            gload_lds16(p + half, &ldsA[ns][dbase + 512]);
        }
        __builtin_amdgcn_s_barrier();
        __builtin_amdgcn_s_setprio(1);
        acc[0][0] = MFMA_I8(a00, b00, acc[0][0], 0, 0, 0);
        acc[0][1] = MFMA_I8(a00, b10, acc[0][1], 0, 0, 0);
        acc[1][0] = MFMA_I8(a10, b00, acc[1][0], 0, 0, 0);
        acc[1][1] = MFMA_I8(a10, b10, acc[1][1], 0, 0, 0);
        acc[0][0] = MFMA_I8(a01, b01, acc[0][0], 0, 0, 0);
        acc[0][1] = MFMA_I8(a01, b11, acc[0][1], 0, 0, 0);
        acc[1][0] = MFMA_I8(a11, b01, acc[1][0], 0, 0, 0);
        acc[1][1] = MFMA_I8(a11, b11, acc[1][1], 0, 0, 0);
        __builtin_amdgcn_s_setprio(0);
        __builtin_amdgcn_s_barrier();

        // ================= phase 1: A rf2,rf3; stage B of t+2 ===============
        const v4i a20 = LA[abase + 256 + c00];
        const v4i a21 = LA[abase + 256 + c01];
        const v4i a30 = LA[abase + 384 + c00];
        const v4i a31 = LA[abase + 384 + c01];
        if (t + 2 < NT) {
            const int ns = (t + 2) & 3;
            const int8_t* p = bS + (size_t)(t + 2) * BKB;
            gload_lds16(p,        &ldsB[ns][dbase]);
            gload_lds16(p + half, &ldsB[ns][dbase + 512]);
        }
        __builtin_amdgcn_s_barrier();
        __builtin_amdgcn_s_setprio(1);
        acc[2][0] = MFMA_I8(a20, b00, acc[2][0], 0, 0, 0);
        acc[2][1] = MFMA_I8(a20, b10, acc[2][1], 0, 0, 0);
        acc[3][0] = MFMA_I8(a30, b00, acc[3][0], 0, 0, 0);
        acc[3][1] = MFMA_I8(a30, b10, acc[3][1], 0, 0, 0);
        acc[2][0] = MFMA_I8(a21, b01, acc[2][0], 0, 0, 0);
        acc[2][1] = MFMA_I8(a21, b11, acc[2][1], 0, 0, 0);
        acc[3][0] = MFMA_I8(a31, b01, acc[3][0], 0, 0, 0);
        acc[3][1] = MFMA_I8(a31, b11, acc[3][1], 0, 0, 0);
        __builtin_amdgcn_s_setprio(0);
        // counted wait: tile t+1's 4 loads are the oldest; keep t+2's 4 in flight
        if (t + 2 < NT) {
            asm volatile("s_waitcnt vmcnt(4)" ::: "memory");
        } else if (t + 1 < NT) {
            asm volatile("s_waitcnt vmcnt(0)" ::: "memory");
        }
        __builtin_amdgcn_sched_barrier(0);
        __builtin_amdgcn_s_barrier();
    }

    // ---- epilogue: y = (acc - wzp*sum_x[m] - zp*sum_w[n] + K*zp*wzp)*(sa*sw) + bias[n]
    const float stot = p_sa[0] * p_sw[0];
    const int zpa = p_zpa[0];
    const int wzp = p_wzp[0];
    const int kzz = K * zpa * wzp;
    const int coll = lane & 31;
    const int rhi = (lane >> 5) * 4;

    #pragma unroll
    for (int cf = 0; cf < 2; ++cf) {
        const int cg = n0 + wc * 64 + cf * 32 + coll;
        const int sw = sum_w[cg];
        const float bb = bias[cg];
        #pragma unroll
        for (int rf = 0; rf < 4; ++rf) {
            const int rbase = m0 + wr * 128 + rf * 32 + rhi;
            #pragma unroll
            for (int r = 0; r < 16; ++r) {
                const int rowg = rbase + (r & 3) + 8 * (r >> 2);
                const int iv = acc[rf][cf][r] - wzp * sum_x[rowg] - zpa * sw + kzz;
                out[(size_t)rowg * N + cg] = (float)iv * stot + bb;
            }
        }
    }
}

// ---------------------------------------------------------------------------
extern "C" void kernel_launch(void* const* d_in, const int* in_sizes, int n_in,
                              void* d_out, int out_size, void* d_ws, size_t ws_size,
                              hipStream_t stream) {
    const float* x     = (const float*)d_in[0];
    const int*   w     = (const int*)d_in[1];
    const float* bias  = (const float*)d_in[2];
    const float* p_sa  = (const float*)d_in[3];
    const int*   p_zpa = (const int*)d_in[4];
    const float* p_sw  = (const float*)d_in[5];
    const int*   p_wzp = (const int*)d_in[6];

    const int N = in_sizes[2];             // OUT
    const int K = in_sizes[1] / N;         // IN
    const int M = in_sizes[0] / K;         // B*S

    int8_t* xq = (int8_t*)d_ws;
    int8_t* wq = xq + (size_t)M * K;
    int* sum_x = (int*)(wq + (size_t)N * K);
    int* sum_w = sum_x + M;

    quant_x_kernel<<<M, 256, 0, stream>>>(x, xq, sum_x, p_sa, p_zpa, K);
    quant_w_kernel<<<N, 256, 0, stream>>>(w, wq, sum_w, K);

    dim3 grid(N / BN, M / BM);
    gemm_i8_kernel<<<grid, 512, 0, stream>>>(xq, wq, sum_x, sum_w, bias,
                                             (float*)d_out, p_sa, p_zpa, p_sw, p_wzp,
                                             M, N, K);
}